// Round 7
// baseline (1174.868 us; speedup 1.0000x reference)
//
#include <hip/hip_runtime.h>
#include <hip/hip_bf16.h>
#include <math.h>

#define HIDDEN   2560
#define NUM_HEADS 80
#define HEAD_DIM 64
#define STATE    128
#define CONV_K   4
#define CHUNK    256
#define INTER    (2*HIDDEN)                 // 5120
#define CONV_DIM (INTER + 2*STATE)          // 5376
#define PROJ     (INTER + CONV_DIM + NUM_HEADS) // 10576
#define PROJ_PAD 10624                      // 83*128
#define NBC      336                        // B,C (256) + dt (80) columns
#define EPS      1e-5f

#define BATCH 2
#define SEQ   2048
#define TOK   (BATCH*SEQ)                   // 4096
#define NC    (SEQ/CHUNK)                   // 8
#define KSPLIT 16
#define KCH   (HIDDEN/KSPLIT)               // 160

typedef __attribute__((ext_vector_type(8))) short bf16x8;
typedef __attribute__((ext_vector_type(4))) float f32x4;

__device__ __forceinline__ unsigned short f2bf(float f){
    union{float f;unsigned u;}v; v.f=f;
    unsigned r = v.u + 0x7fffu + ((v.u>>16)&1u);
    return (unsigned short)(r>>16);
}
__device__ __forceinline__ float bf2f(unsigned short s){
    union{unsigned u;float f;}v; v.u = ((unsigned)s)<<16; return v.f;
}
__device__ __forceinline__ void unpack8(uint4 u, float* e){
    e[0]=bf2f((unsigned short)(u.x&0xffff)); e[1]=bf2f((unsigned short)(u.x>>16));
    e[2]=bf2f((unsigned short)(u.y&0xffff)); e[3]=bf2f((unsigned short)(u.y>>16));
    e[4]=bf2f((unsigned short)(u.z&0xffff)); e[5]=bf2f((unsigned short)(u.z>>16));
    e[6]=bf2f((unsigned short)(u.w&0xffff)); e[7]=bf2f((unsigned short)(u.w>>16));
}

__device__ __forceinline__ void gld16(const void* g, void* l){
    __builtin_amdgcn_global_load_lds((const __attribute__((address_space(1))) void*)g,
                                     (__attribute__((address_space(3))) void*)l, 16, 0, 0);
}

// =============== bf16 MFMA GEMM (NT): C[m][n] = sum_k A[m][k]*B[n][k] ==============
// 128x128 tile, BK=64, 4 waves (2x2), each wave 64x64 via 4x4 frags of 16x16x32.
// M,N multiples of 128; K multiple of 64. XCD-aware swizzle: XCD (bid&7) owns
// gridDim.y/8 consecutive m-rows, sweeps n with m fastest (A L2-resident,
// B-panel shared by consecutive blocks on same XCD).
template<bool BF16OUT>
__global__ __launch_bounds__(256) void gemm_bf16(const unsigned short* __restrict__ A, int lda,
                                                 const unsigned short* __restrict__ B, int ldb,
                                                 void* __restrict__ Cv, int ldc, int K) {
    __shared__ unsigned short As[128][64];
    __shared__ unsigned short Bs[128][64];
    int tid = threadIdx.x;
    int lane = tid & 63, wid = tid >> 6;
    int wr = wid >> 1, wc = wid & 1;

    int bm, bn;
    if ((gridDim.y & 7) == 0) {
        int bid   = blockIdx.y * gridDim.x + blockIdx.x;
        int xcd   = bid & 7;
        int local = bid >> 3;
        int mrows = gridDim.y >> 3;
        bm = (xcd * mrows + (local % mrows)) * 128;
        bn = (local / mrows) * 128;
    } else {
        bm = blockIdx.y * 128;
        bn = blockIdx.x * 128;
    }

    f32x4 acc[4][4];
    #pragma unroll
    for (int i=0;i<4;i++)
        #pragma unroll
        for (int j=0;j<4;j++) acc[i][j] = (f32x4){0.f,0.f,0.f,0.f};

    int srow_off = lane >> 3;            // 0..7 within 8-row chunk
    int sslot    = lane & 7;             // dest 16B slot

    for (int k0 = 0; k0 < K; k0 += 64) {
        #pragma unroll
        for (int q=0;q<4;q++){
            int brow = (wid*4+q)*8;
            int row  = brow + srow_off;
            int sl   = sslot ^ (row & 7);            // inverse-swizzled source slot
            gld16(A + (size_t)(bm + row)*lda + k0 + sl*8, &As[brow][0]);
            gld16(B + (size_t)(bn + row)*ldb + k0 + sl*8, &Bs[brow][0]);
        }
        __syncthreads();
        #pragma unroll
        for (int kk=0; kk<64; kk+=32){
            bf16x8 a[4], b[4];
            #pragma unroll
            for (int i=0;i<4;i++){
                int row = wr*64 + i*16 + (lane&15);
                int slot = ((kk>>3) + (lane>>4)) ^ (row & 7);
                a[i] = *(const bf16x8*)&As[row][slot*8];
            }
            #pragma unroll
            for (int j=0;j<4;j++){
                int row = wc*64 + j*16 + (lane&15);
                int slot = ((kk>>3) + (lane>>4)) ^ (row & 7);
                b[j] = *(const bf16x8*)&Bs[row][slot*8];
            }
            #pragma unroll
            for (int i=0;i<4;i++)
                #pragma unroll
                for (int j=0;j<4;j++)
                    acc[i][j] = __builtin_amdgcn_mfma_f32_16x16x32_bf16(a[i], b[j], acc[i][j], 0, 0, 0);
        }
        __syncthreads();
    }
    // C/D layout: col = lane&15, row = (lane>>4)*4 + reg
    #pragma unroll
    for (int i=0;i<4;i++){
        int row0 = bm + wr*64 + i*16 + (lane>>4)*4;
        #pragma unroll
        for (int j=0;j<4;j++){
            int col = bn + wc*64 + j*16 + (lane&15);
            #pragma unroll
            for (int r=0;r<4;r++){
                if (BF16OUT)
                    ((unsigned short*)Cv)[(size_t)(row0+r)*ldc + col] = f2bf(acc[i][j][r]);
                else
                    ((float*)Cv)[(size_t)(row0+r)*ldc + col] = acc[i][j][r];
            }
        }
    }
}

// ---------------- fp32→bf16 conversion kernels --------------------------------------
__global__ __launch_bounds__(256) void cvt_bf16(const float* __restrict__ in,
                                                unsigned short* __restrict__ out, size_t n4){
    size_t i4 = (size_t)blockIdx.x*256 + threadIdx.x;
    if (i4 >= n4) return;
    size_t i = i4*4;
    float4 v = *(const float4*)(in+i);
    ushort4 o; o.x=f2bf(v.x); o.y=f2bf(v.y); o.z=f2bf(v.z); o.w=f2bf(v.w);
    *(ushort4*)(out+i) = o;
}
__global__ __launch_bounds__(256) void cvt_w1(const float* __restrict__ in,
                                              unsigned short* __restrict__ out){
    size_t i4 = (size_t)blockIdx.x*256 + threadIdx.x;
    if (i4 >= (size_t)PROJ_PAD*HIDDEN/4) return;
    size_t i = i4*4;
    int row = (int)(i / HIDDEN);
    ushort4 o;
    if (row < PROJ){
        float4 v = *(const float4*)(in+i);
        o.x=f2bf(v.x); o.y=f2bf(v.y); o.z=f2bf(v.z); o.w=f2bf(v.w);
    } else { o.x=o.y=o.z=o.w=0; }
    *(ushort4*)(out+i) = o;
}

// ---------------- split-K fp32 GEMM for the 336 B/C/dt columns ----------------------
#define BM 128
#define BN 128
#define BKK 16
__global__ __launch_bounds__(256) void gemm_bc_splitk(const float* __restrict__ A, int lda,
                                                      const float* __restrict__ B, int ldb,
                                                      float* __restrict__ Cpart) {
    __shared__ float As[BKK][BM];
    __shared__ float Bs[BKK][BN];
    int tid = threadIdx.x;
    int bm = blockIdx.y * BM, bn = blockIdx.x * BN;
    int z  = blockIdx.z;
    int ty = tid >> 4, tx = tid & 15;
    float acc[8][8];
    #pragma unroll
    for (int i=0;i<8;i++)
        #pragma unroll
        for (int j=0;j<8;j++) acc[i][j]=0.f;
    int lr = tid >> 1, lk = (tid & 1) * 8;
    for (int k0 = z*KCH; k0 < (z+1)*KCH; k0 += BKK) {
        #pragma unroll
        for (int u=0;u<8;u++)
            As[lk+u][lr] = A[(size_t)(bm+lr)*lda + k0 + lk + u];
        int ncol = bn + lr;
        if (ncol < NBC) {
            #pragma unroll
            for (int u=0;u<8;u++)
                Bs[lk+u][lr] = B[(size_t)ncol*ldb + k0 + lk + u];
        } else {
            #pragma unroll
            for (int u=0;u<8;u++) Bs[lk+u][lr] = 0.f;
        }
        __syncthreads();
        #pragma unroll
        for (int k=0;k<BKK;k++){
            float a[8], bb[8];
            #pragma unroll
            for (int i=0;i<8;i++) a[i] = As[k][ty*8+i];
            #pragma unroll
            for (int j=0;j<8;j++) bb[j] = Bs[k][tx*8+j];
            #pragma unroll
            for (int i=0;i<8;i++)
                #pragma unroll
                for (int j=0;j<8;j++) acc[i][j] += a[i]*bb[j];
        }
        __syncthreads();
    }
    float* Cz = Cpart + (size_t)z*TOK*NBC;
    #pragma unroll
    for (int i=0;i<8;i++){
        int m = bm + ty*8 + i;
        #pragma unroll
        for (int j=0;j<8;j++){
            int n = bn + tx*8 + j;
            if (n < NBC) Cz[(size_t)m*NBC + n] = acc[i][j];
        }
    }
}

// fixed-order reduce over the KSPLIT partials (deterministic) + fused dt softplus
__global__ __launch_bounds__(256) void reduce_bc(const float* __restrict__ part,
                                                 const float* __restrict__ dt_bias,
                                                 float* __restrict__ outBC,
                                                 float* __restrict__ dtbuf) {
    size_t i4 = (size_t)blockIdx.x*256 + threadIdx.x;
    if (i4 >= (size_t)TOK*NBC/4) return;
    size_t i = i4*4;
    float4 s = *(const float4*)(part + i);
    #pragma unroll
    for (int z=1; z<KSPLIT; z++){
        float4 v = *(const float4*)(part + (size_t)z*TOK*NBC + i);
        s.x += v.x; s.y += v.y; s.z += v.z; s.w += v.w;
    }
    int col = (int)(i % NBC);
    int t   = (int)(i / NBC);
    if (col < 256) {
        *(float4*)(outBC + i) = s;
    } else {
        int h = col - 256;
        float e[4] = {s.x, s.y, s.z, s.w};
        #pragma unroll
        for (int u=0;u<4;u++){
            float xv = e[u] + dt_bias[h+u];
            float sp = (xv > 20.f) ? xv : log1pf(expf(xv));
            e[u] = fminf(fmaxf(sp, 0.f), 100.f);
        }
        float4 o; o.x=e[0]; o.y=e[1]; o.z=e[2]; o.w=e[3];
        *(float4*)(dtbuf + (size_t)t*NUM_HEADS + h) = o;
    }
}

// ---------------- conv+SiLU, X part (bf16 in, bf16 out), 8-wide ---------------------
__global__ __launch_bounds__(256) void conv_x_kernel(const unsigned short* __restrict__ projb,
                                                     const float* __restrict__ cw,
                                                     const float* __restrict__ cb,
                                                     unsigned short* __restrict__ xBC_X) {
    size_t i8 = (size_t)blockIdx.x*256 + threadIdx.x;
    if (i8 >= (size_t)TOK*INTER/8) return;
    int dd = (int)(i8 % (INTER/8))*8;
    int t  = (int)(i8 / (INTER/8));
    int b = t / SEQ, sl = t % SEQ;
    float acc[8];
    #pragma unroll
    for (int u=0;u<8;u++) acc[u] = cb[dd+u];
    #pragma unroll
    for (int j=0;j<CONV_K;j++){
        int sp = sl - (CONV_K-1) + j;
        if (sp >= 0){
            float e[8];
            unpack8(*(const uint4*)(projb + ((size_t)(b*SEQ+sp))*PROJ_PAD + INTER + dd), e);
            #pragma unroll
            for (int u=0;u<8;u++) acc[u] += cw[(dd+u)*CONV_K+j]*e[u];
        }
    }
    ushort4 o0, o1;
    float v0 = acc[0]/(1.f+expf(-acc[0])), v1 = acc[1]/(1.f+expf(-acc[1]));
    float v2 = acc[2]/(1.f+expf(-acc[2])), v3 = acc[3]/(1.f+expf(-acc[3]));
    float v4 = acc[4]/(1.f+expf(-acc[4])), v5 = acc[5]/(1.f+expf(-acc[5]));
    float v6 = acc[6]/(1.f+expf(-acc[6])), v7 = acc[7]/(1.f+expf(-acc[7]));
    o0.x=f2bf(v0); o0.y=f2bf(v1); o0.z=f2bf(v2); o0.w=f2bf(v3);
    o1.x=f2bf(v4); o1.y=f2bf(v5); o1.z=f2bf(v6); o1.w=f2bf(v7);
    *(ushort4*)(xBC_X + (size_t)t*INTER + dd)     = o0;
    *(ushort4*)(xBC_X + (size_t)t*INTER + dd + 4) = o1;
}

// ---------------- conv+SiLU, B/C part (fp32 in/out) + bf16 CT -----------------------
__global__ __launch_bounds__(256) void conv_bc_kernel(const float* __restrict__ projBC,
                                                      const float* __restrict__ cw,
                                                      const float* __restrict__ cb,
                                                      float* __restrict__ xBC_BC,
                                                      unsigned short* __restrict__ CT) {
    int idx = blockIdx.x*256 + threadIdx.x;
    if (idx >= TOK*256) return;
    int d = idx & 255;            // 0..255 -> conv dim 5120+d
    int t = idx >> 8;
    int b = t / SEQ, sl = t % SEQ;
    int dc = INTER + d;
    float acc = cb[dc];
    #pragma unroll
    for (int j=0;j<CONV_K;j++){
        int sp = sl - (CONV_K-1) + j;
        if (sp >= 0)
            acc += cw[dc*CONV_K+j] * projBC[((size_t)(b*SEQ+sp))*NBC + d];
    }
    float val = acc / (1.f + expf(-acc));
    xBC_BC[(size_t)t*256 + d] = val;
    if (d >= 128) {
        int n = d - 128;
        CT[((size_t)(b*STATE + n))*SEQ + sl] = f2bf(val);
    }
}

// ---------------- per-chunk inclusive cumsum of dA = A*dt ---------------------------
__global__ __launch_bounds__(256) void cumsum_kernel(const float* __restrict__ dtbuf,
                                                     const float* __restrict__ A_log,
                                                     float* __restrict__ A_cum) {
    int c = blockIdx.x, h = blockIdx.y, b = blockIdx.z;
    int l = threadIdx.x;
    float A = -expf(A_log[h]);
    float v = A * dtbuf[(size_t)(b*SEQ + c*CHUNK + l)*NUM_HEADS + h];
    __shared__ float buf[CHUNK];
    buf[l] = v;
    __syncthreads();
    for (int off=1; off<CHUNK; off<<=1){
        float t = (l>=off) ? buf[l-off] : 0.f;
        __syncthreads();
        buf[l] += t;
        __syncthreads();
    }
    A_cum[((size_t)b*NUM_HEADS + h)*SEQ + c*CHUNK + l] = buf[l];
}

// ---------------- G[s][l] = C[l] . B[s]  (head-shared), bf16 out --------------------
__global__ __launch_bounds__(256) void g_kernel(const float* __restrict__ xBC_BC,
                                                unsigned short* __restrict__ G) {
    int p = blockIdx.x, c = blockIdx.y, b = blockIdx.z;
    int lt = 0, a0 = 0;
    while (a0 + lt + 1 <= p) { a0 += lt + 1; lt++; }
    int st = p - a0;
    int l0 = lt*64, s0 = st*64;
    __shared__ float Cs[64][68];
    __shared__ float Bs[64][68];
    int tid = threadIdx.x, ty = tid >> 4, tx = tid & 15;
    float acc[4][4];
    #pragma unroll
    for (int i=0;i<4;i++)
        #pragma unroll
        for (int j=0;j<4;j++) acc[i][j]=0.f;

    size_t rowC = ((size_t)(b*SEQ + c*CHUNK + l0))*256 + 128;
    size_t rowB = ((size_t)(b*SEQ + c*CHUNK + s0))*256;
    for (int kc=0; kc<2; kc++){
        #pragma unroll
        for (int it=0; it<4; it++){
            int f = tid + it*256;
            int r = f >> 4, c4 = f & 15;
            float4 cv = *(const float4*)(xBC_BC + rowC + (size_t)r*256 + kc*64 + c4*4);
            float4 bv = *(const float4*)(xBC_BC + rowB + (size_t)r*256 + kc*64 + c4*4);
            *(float4*)&Cs[r][c4*4] = cv;
            *(float4*)&Bs[r][c4*4] = bv;
        }
        __syncthreads();
        #pragma unroll 8
        for (int k=0;k<64;k++){
            float a[4], bb[4];
            #pragma unroll
            for (int i=0;i<4;i++) a[i] = Cs[ty*4+i][k];
            #pragma unroll
            for (int j=0;j<4;j++) bb[j] = Bs[tx*4+j][k];
            #pragma unroll
            for (int i=0;i<4;i++)
                #pragma unroll
                for (int j=0;j<4;j++) acc[i][j] += a[i]*bb[j];
        }
        __syncthreads();
    }
    size_t Gb = ((size_t)(b*NC + c)) << 16;
    #pragma unroll
    for (int j=0;j<4;j++){
        ushort4 g4;
        g4.x = f2bf(acc[0][j]); g4.y = f2bf(acc[1][j]);
        g4.z = f2bf(acc[2][j]); g4.w = f2bf(acc[3][j]);
        *(ushort4*)(G + Gb + (size_t)(s0 + tx*4 + j)*256 + l0 + ty*4) = g4;
    }
}

// ---------------- states[n][p] = sum_l (B[l][n]*wt[l]) * X[l][p] --------------------
__global__ __launch_bounds__(256) void states_gemm(const float* __restrict__ xBC_BC,
                                                   const unsigned short* __restrict__ xBC_X,
                                                   const float* __restrict__ dtbuf,
                                                   const float* __restrict__ A_cum,
                                                   float* __restrict__ states) {
    int c = blockIdx.x, h = blockIdx.y, b = blockIdx.z;
    __shared__ float Bw[64][132];
    __shared__ float Xs[64][68];
    __shared__ float ac[CHUNK], dts[CHUNK];
    int tid = threadIdx.x;
    ac[tid]  = A_cum[((size_t)(b*NUM_HEADS + h))*SEQ + c*CHUNK + tid];
    dts[tid] = dtbuf[((size_t)(b*SEQ + c*CHUNK + tid))*NUM_HEADS + h];
    __syncthreads();
    float Alast = ac[CHUNK-1];
    int ty = tid >> 4, tx = tid & 15;
    float acc[8][4];
    #pragma unroll
    for (int i=0;i<8;i++)
        #pragma unroll
        for (int j=0;j<4;j++) acc[i][j]=0.f;

    size_t rowBC = ((size_t)(b*SEQ + c*CHUNK))*256;
    size_t rowX  = ((size_t)(b*SEQ + c*CHUNK))*INTER + h*HEAD_DIM;
    for (int kc=0; kc<4; kc++){
        #pragma unroll
        for (int it=0; it<8; it++){
            int f = tid + it*256;
            int r = f >> 5, c4 = f & 31;
            int l = kc*64 + r;
            float w = expf(Alast - ac[l]) * dts[l];
            float4 bv = *(const float4*)(xBC_BC + rowBC + (size_t)l*256 + c4*4);
            float4 o; o.x = bv.x*w; o.y = bv.y*w; o.z = bv.z*w; o.w = bv.w*w;
            *(float4*)&Bw[r][c4*4] = o;
        }
        #pragma unroll
        for (int it=0; it<2; it++){
            int f = tid + it*256;
            int r = f >> 3, c8 = f & 7;
            int l = kc*64 + r;
            float e[8];
            unpack8(*(const uint4*)(xBC_X + rowX + (size_t)l*INTER + c8*8), e);
            #pragma unroll
            for (int u=0;u<8;u++) Xs[r][c8*8+u] = e[u];
        }
        __syncthreads();
        #pragma unroll 4
        for (int k=0;k<64;k++){
            float av[8], bv[4];
            *(float4*)&av[0] = *(float4*)&Bw[k][ty*8];
            *(float4*)&av[4] = *(float4*)&Bw[k][ty*8+4];
            *(float4*)&bv[0] = *(float4*)&Xs[k][tx*4];
            #pragma unroll
            for (int i=0;i<8;i++)
                #pragma unroll
                for (int j=0;j<4;j++) acc[i][j] += av[i]*bv[j];
        }
        __syncthreads();
    }
    size_t sb = ((size_t)((b*NC + c)*NUM_HEADS + h))*(HEAD_DIM*STATE);
    #pragma unroll
    for (int i=0;i<8;i++){
        float4 o; o.x=acc[i][0]; o.y=acc[i][1]; o.z=acc[i][2]; o.w=acc[i][3];
        *(float4*)(states + sb + (size_t)(ty*8+i)*64 + tx*4) = o;
    }
}

// ---------------- inter-chunk recurrence (in place) ---------------------------------
__global__ __launch_bounds__(256) void recur_kernel(const float* __restrict__ A_cum,
                                                    float* __restrict__ states) {
    int h = blockIdx.x, b = blockIdx.y;
    int tid = threadIdx.x;
    float Srun[32];
    #pragma unroll
    for (int i=0;i<32;i++) Srun[i]=0.f;
    const float* acum = A_cum + ((size_t)b*NUM_HEADS + h)*SEQ;
    for (int c=0;c<NC;c++){
        float alast = acum[c*CHUNK + CHUNK-1];
        float dec = expf(alast);
        size_t base = ((size_t)((b*NC + c)*NUM_HEADS + h))*(HEAD_DIM*STATE);
        #pragma unroll
        for (int i=0;i<32;i++){
            size_t idx = base + (size_t)tid + (size_t)i*256;
            float raw = states[idx];
            states[idx] = Srun[i];
            Srun[i] = Srun[i]*dec + raw;
        }
    }
}

// ---------------- Y = Y_off + Y_diag + D*X  (tiled GEMMs), bf16 out -----------------
__global__ __launch_bounds__(256) void yscan2_kernel(const unsigned short* __restrict__ G,
                                                     const unsigned short* __restrict__ CT,
                                                     const unsigned short* __restrict__ xBC_X,
                                                     const float* __restrict__ dtbuf,
                                                     const float* __restrict__ A_cum,
                                                     const float* __restrict__ states,
                                                     const float* __restrict__ Dvec,
                                                     unsigned short* __restrict__ projb) {
    int xb = blockIdx.x;
    int c = xb >> 2, lt = xb & 3;
    int h = blockIdx.y, b = blockIdx.z;
    int l0 = lt*64;
    __shared__ float sm[2*64*68];
    float* T0 = sm;
    float* T1 = sm + 64*68;
    __shared__ float ac[CHUNK], dts[CHUNK];
    int tid = threadIdx.x, ty = tid >> 4, tx = tid & 15;
    ac[tid]  = A_cum[((size_t)(b*NUM_HEADS + h))*SEQ + c*CHUNK + tid];
    dts[tid] = dtbuf[((size_t)(b*SEQ + c*CHUNK + tid))*NUM_HEADS + h];
    __syncthreads();

    float yacc[4][4];
    #pragma unroll
    for (int i=0;i<4;i++)
        #pragma unroll
        for (int j=0;j<4;j++) yacc[i][j]=0.f;

    // ---- phase 1: Y_off = C @ states, K=n=128 in 2 chunks ----
    size_t stb = ((size_t)((b*NC + c)*NUM_HEADS + h))*(HEAD_DIM*STATE);
    for (int kc=0; kc<2; kc++){
        #pragma unroll
        for (int it=0; it<2; it++){
            int f = tid + it*256;
            int n = f >> 3, g = f & 7;
            float e[8];
            unpack8(*(const uint4*)(CT + ((size_t)(b*STATE + kc*64 + n))*SEQ + c*CHUNK + l0 + g*8), e);
            #pragma unroll
            for (int u=0;u<8;u++) T0[n*68 + g*8 + u] = e[u];
        }
        #pragma unroll
        for (int it=0; it<4; it++){
            int f = tid + it*256;
            int n = f >> 4, c4 = f & 15;
            *(float4*)&T1[n*68 + c4*4] =
                *(const float4*)(states + stb + (size_t)(kc*64 + n)*64 + c4*4);
        }
        __syncthreads();
        #pragma unroll 4
        for (int k=0;k<64;k++){
            float av[4], bv[4];
            *(float4*)&av[0] = *(float4*)&T0[k*68 + ty*4];
            *(float4*)&bv[0] = *(float4*)&T1[k*68 + tx*4];
            #pragma unroll
            for (int i=0;i<4;i++)
                #pragma unroll
                for (int j=0;j<4;j++) yacc[i][j] += av[i]*bv[j];
        }
        __syncthreads();
    }
    #pragma unroll
    for (int i=0;i<4;i++){
        float el = expf(ac[l0 + ty*4 + i]);
        #pragma unroll
        for (int j=0;j<4;j++) yacc[i][j] *= el;
    }

    // ---- phase 2: Y_diag over causal s-tiles ----
    float Dh = Dvec[h];
    size_t Gb = ((size_t)(b*NC + c)) << 16;
    size_t rowX = ((size_t)(b*SEQ + c*CHUNK))*INTER + h*HEAD_DIM;
    for (int st=0; st<=lt; st++){
        int s0 = st*64;
        #pragma unroll
        for (int it=0; it<2; it++){
            int f = tid + it*256;
            int s = f >> 3, g = f & 7;
            float e[8];
            unpack8(*(const uint4*)(G + Gb + (size_t)(s0 + s)*256 + l0 + g*8), e);
            float asv = ac[s0 + s];
            float dtv = dts[s0 + s];
            int sg = s0 + s;
            #pragma unroll
            for (int u2=0; u2<8; u2++){
                int lg = l0 + g*8 + u2;
                float w = 0.f;
                if (sg <= lg) w = expf(ac[lg] - asv) * dtv;
                T0[s*68 + g*8 + u2] = e[u2]*w;
            }
        }
        #pragma unroll
        for (int it=0; it<2; it++){
            int f = tid + it*256;
            int r = f >> 3, c8 = f & 7;
            float e[8];
            unpack8(*(const uint4*)(xBC_X + rowX + (size_t)(s0 + r)*INTER + c8*8), e);
            #pragma unroll
            for (int u=0;u<8;u++) T1[r*68 + c8*8 + u] = e[u];
        }
        __syncthreads();
        #pragma unroll 4
        for (int k=0;k<64;k++){
            float av[4], bv[4];
            *(float4*)&av[0] = *(float4*)&T0[k*68 + ty*4];
            *(float4*)&bv[0] = *(float4*)&T1[k*68 + tx*4];
            #pragma unroll
            for (int i=0;i<4;i++)
                #pragma unroll
                for (int j=0;j<4;j++) yacc[i][j] += av[i]*bv[j];
        }
        if (st == lt){
            #pragma unroll
            for (int i=0;i<4;i++)
                #pragma unroll
                for (int j=0;j<4;j++)
                    yacc[i][j] += Dh * T1[(ty*4+i)*68 + tx*4+j];
        }
        __syncthreads();
    }

    // ---- store bf16 Y into projb[:, INTER + h*64 ...] ----
    #pragma unroll
    for (int i=0;i<4;i++)
        #pragma unroll
        for (int j=0;j<4;j++)
            T0[(ty*4+i)*68 + tx*4+j] = yacc[i][j];
    __syncthreads();
    #pragma unroll
    for (int it=0; it<4; it++){
        int f = tid + it*256;
        int r = f >> 4, c4 = f & 15;
        ushort4 o;
        o.x = f2bf(T0[r*68 + c4*4+0]); o.y = f2bf(T0[r*68 + c4*4+1]);
        o.z = f2bf(T0[r*68 + c4*4+2]); o.w = f2bf(T0[r*68 + c4*4+3]);
        *(ushort4*)(projb + ((size_t)(b*SEQ + c*CHUNK + l0 + r))*PROJ_PAD + INTER + h*HEAD_DIM + c4*4) = o;
    }
}

// ---------------- gate * silu + RMSNorm -> packed bf16 y ----------------------------
__global__ __launch_bounds__(256) void gate_norm_kernel(const unsigned short* __restrict__ projb,
                                                        const float* __restrict__ normw,
                                                        unsigned short* __restrict__ yb) {
    int t = blockIdx.x;
    int tid = threadIdx.x;
    const unsigned short* row = projb + (size_t)t*PROJ_PAD;
    __shared__ float red[4];
    float vals[20];
    float ss = 0.f;
    #pragma unroll
    for (int i=0;i<5;i++){
        int j = (tid + i*256)*4;
        ushort4 g4 = *(const ushort4*)(row + j);
        ushort4 y4 = *(const ushort4*)(row + INTER + j);
        #pragma unroll
        for (int u=0;u<4;u++){
            float g = bf2f(((const unsigned short*)&g4)[u]);
            float y = bf2f(((const unsigned short*)&y4)[u]);
            float gv = g / (1.f + expf(-g));
            float v = y * gv;
            vals[i*4+u] = v;
            ss += v*v;
        }
    }
    #pragma unroll
    for (int off=32; off; off>>=1) ss += __shfl_xor(ss, off);
    if ((tid&63)==0) red[tid>>6] = ss;
    __syncthreads();
    float tot = red[0]+red[1]+red[2]+red[3];
    float inv = rsqrtf(tot/(float)INTER + EPS);
    #pragma unroll
    for (int i=0;i<5;i++){
        int j = (tid + i*256)*4;
        ushort4 o;
        o.x = f2bf(vals[i*4+0] * inv * normw[j+0]);
        o.y = f2bf(vals[i*4+1] * inv * normw[j+1]);
        o.z = f2bf(vals[i*4+2] * inv * normw[j+2]);
        o.w = f2bf(vals[i*4+3] * inv * normw[j+3]);
        *(ushort4*)(yb + (size_t)t*INTER + j) = o;
    }
}

// ------------------------------------------------------------------------------------
extern "C" void kernel_launch(void* const* d_in, const int* in_sizes, int n_in,
                              void* d_out, int out_size, void* d_ws, size_t ws_size,
                              hipStream_t stream) {
    const float* x        = (const float*)d_in[0];
    const float* in_w     = (const float*)d_in[1];
    const float* conv_w   = (const float*)d_in[2];
    const float* conv_b   = (const float*)d_in[3];
    const float* A_log    = (const float*)d_in[4];
    const float* Dvec     = (const float*)d_in[5];
    const float* dt_bias  = (const float*)d_in[6];
    const float* norm_w   = (const float*)d_in[7];
    const float* out_w    = (const float*)d_in[8];
    float* out = (float*)d_out;
    (void)ws_size; (void)n_in; (void)in_sizes; (void)out_size;

    // ---- workspace layout (bytes), total ~275 MB ----
    const size_t PROJB   = (size_t)TOK*PROJ_PAD*2;          // 87.0 MB
    const size_t PROJBCB = (size_t)TOK*NBC*4;               //  5.5 MB
    const size_t XBCXB   = (size_t)TOK*INTER*2;             // 41.9 MB
    const size_t XBCBCB  = (size_t)TOK*256*4;               //  4.2 MB
    const size_t CTB     = (size_t)BATCH*STATE*SEQ*2;       //  1.0 MB
    const size_t GBYTES  = (size_t)BATCH*NC*CHUNK*CHUNK*2;  //  2.1 MB
    const size_t DTB     = (size_t)TOK*NUM_HEADS*4;         //  1.3 MB
    const size_t ACUMB   = DTB;
    const size_t STB     = (size_t)BATCH*NC*NUM_HEADS*HEAD_DIM*STATE*4; // 41.9 MB
    const size_t XB      = (size_t)TOK*HIDDEN*2;            // 21.0 MB
    const size_t YB      = (size_t)TOK*INTER*2;             // 41.9 MB

    char* base = (char*)d_ws;
    size_t off = 0;
    unsigned short* projb  = (unsigned short*)(base + off); off += PROJB;
    float* projBC          = (float*)(base + off);          off += PROJBCB;
    unsigned short* xBC_X  = (unsigned short*)(base + off); off += XBCXB;
    float* xBC_BC          = (float*)(base + off);          off += XBCBCB;
    unsigned short* CTp    = (unsigned short*)(base + off); off += CTB;
    unsigned short* Gp     = (unsigned short*)(base + off); off += GBYTES;
    float* dtbuf           = (float*)(base + off);          off += DTB;
    float* A_cum           = (float*)(base + off);          off += ACUMB;
    float* states          = (float*)(base + off);          off += STB;
    char*  T               = base + off;
    unsigned short* xb  = (unsigned short*)T;          // GEMM1 phase
    unsigned short* w1b = (unsigned short*)(T + XB);   // GEMM1 phase
    float* bcpart       = (float*)T;                   // split-K partials (after GEMM1; 88 MB)
    unsigned short* yb  = (unsigned short*)T;          // GEMM2 phase (aliases all above)
    unsigned short* w2b = (unsigned short*)(T + YB);   // GEMM2 phase

    const size_t XB_E = (size_t)TOK*HIDDEN;
    const size_t W1_E = (size_t)PROJ_PAD*HIDDEN;
    const size_t W2_E = (size_t)HIDDEN*INTER;

    // 0. conversions for GEMM1
    cvt_bf16<<<(unsigned)((XB_E/4+255)/256), 256, 0, stream>>>(x, xb, XB_E/4);
    cvt_w1<<<(unsigned)((W1_E/4+255)/256), 256, 0, stream>>>(in_w, w1b);

    // 1. proj = x @ in_w^T  (bf16 MFMA, bf16 out, padded N, XCD swizzle)
    gemm_bf16<true><<<dim3(PROJ_PAD/128, TOK/128), 256, 0, stream>>>(xb, HIDDEN, w1b, HIDDEN,
                                                                     projb, PROJ_PAD, HIDDEN);
    // 1b. B/C/dt columns (336) in fp32 via split-K (partials alias dead xb/w1b)
    gemm_bc_splitk<<<dim3((NBC+BN-1)/BN, TOK/BM, KSPLIT), 256, 0, stream>>>(
        x, HIDDEN, in_w + (size_t)(INTER+INTER)*HIDDEN, HIDDEN, bcpart);
    reduce_bc<<<(unsigned)(((size_t)TOK*NBC/4+255)/256), 256, 0, stream>>>(bcpart, dt_bias, projBC, dtbuf);

    // 2. depthwise conv + silu
    conv_x_kernel<<<(unsigned)(((size_t)TOK*INTER/8+255)/256), 256, 0, stream>>>(projb, conv_w, conv_b, xBC_X);
    conv_bc_kernel<<<(TOK*256+255)/256, 256, 0, stream>>>(projBC, conv_w, conv_b, xBC_BC, CTp);
    // 2b. w2 conversion (after reduce has consumed partials — aliased region)
    cvt_bf16<<<(unsigned)((W2_E/4+255)/256), 256, 0, stream>>>(out_w, w2b, W2_E/4);
    // 3. cumsum
    cumsum_kernel<<<dim3(NC, NUM_HEADS, BATCH), 256, 0, stream>>>(dtbuf, A_log, A_cum);
    // 4. G = C.B^T (head-shared)
    g_kernel<<<dim3(10, NC, BATCH), 256, 0, stream>>>(xBC_BC, Gp);
    // 5. per-chunk states
    states_gemm<<<dim3(NC, NUM_HEADS, BATCH), 256, 0, stream>>>(xBC_BC, xBC_X, dtbuf, A_cum, states);
    // 6. inter-chunk recurrence
    recur_kernel<<<dim3(NUM_HEADS, BATCH), 256, 0, stream>>>(A_cum, states);
    // 7. Y = Y_off + Y_diag + D*X  -> bf16 into projb
    yscan2_kernel<<<dim3(NC*4, NUM_HEADS, BATCH), 256, 0, stream>>>(Gp, CTp, xBC_X, dtbuf, A_cum, states, Dvec, projb);
    // 8. gate + RMSNorm -> bf16 y
    gate_norm_kernel<<<TOK, 256, 0, stream>>>(projb, norm_w, yb);
    // 9. out = y @ out_w^T  (bf16 MFMA, fp32 out, XCD swizzle)
    gemm_bf16<false><<<dim3(HIDDEN/128, TOK/128), 256, 0, stream>>>(yb, INTER, w2b, INTER,
                                                                    out, HIDDEN, INTER);
}

// Round 8
// 874.671 us; speedup vs baseline: 1.3432x; 1.3432x over previous
//
#include <hip/hip_runtime.h>
#include <hip/hip_bf16.h>
#include <math.h>

#define HIDDEN   2560
#define NUM_HEADS 80
#define HEAD_DIM 64
#define STATE    128
#define CONV_K   4
#define CHUNK    256
#define INTER    (2*HIDDEN)                 // 5120
#define CONV_DIM (INTER + 2*STATE)          // 5376
#define PROJ     (INTER + CONV_DIM + NUM_HEADS) // 10576
#define PROJ_PAD 10624                      // 83*128
#define NBC      336                        // B,C (256) + dt (80) columns
#define EPS      1e-5f

#define BATCH 2
#define SEQ   2048
#define TOK   (BATCH*SEQ)                   // 4096
#define NC    (SEQ/CHUNK)                   // 8
#define KSPLIT 16
#define KCH   (HIDDEN/KSPLIT)               // 160

typedef __attribute__((ext_vector_type(8))) short bf16x8;
typedef __attribute__((ext_vector_type(4))) float f32x4;

#define MFMA16(a,b,c) __builtin_amdgcn_mfma_f32_16x16x32_bf16((a),(b),(c),0,0,0)

__device__ __forceinline__ unsigned short f2bf(float f){
    union{float f;unsigned u;}v; v.f=f;
    unsigned r = v.u + 0x7fffu + ((v.u>>16)&1u);
    return (unsigned short)(r>>16);
}
__device__ __forceinline__ float bf2f(unsigned short s){
    union{unsigned u;float f;}v; v.u = ((unsigned)s)<<16; return v.f;
}
__device__ __forceinline__ void unpack8(uint4 u, float* e){
    e[0]=bf2f((unsigned short)(u.x&0xffff)); e[1]=bf2f((unsigned short)(u.x>>16));
    e[2]=bf2f((unsigned short)(u.y&0xffff)); e[3]=bf2f((unsigned short)(u.y>>16));
    e[4]=bf2f((unsigned short)(u.z&0xffff)); e[5]=bf2f((unsigned short)(u.z>>16));
    e[6]=bf2f((unsigned short)(u.w&0xffff)); e[7]=bf2f((unsigned short)(u.w>>16));
}

__device__ __forceinline__ void gld16(const void* g, void* l){
    __builtin_amdgcn_global_load_lds((const __attribute__((address_space(1))) void*)g,
                                     (__attribute__((address_space(3))) void*)l, 16, 0, 0);
}

// =============== bf16 MFMA GEMM (NT): C[m][n] = sum_k A[m][k]*B[n][k] ==============
template<bool BF16OUT>
__global__ __launch_bounds__(256) void gemm_bf16(const unsigned short* __restrict__ A, int lda,
                                                 const unsigned short* __restrict__ B, int ldb,
                                                 void* __restrict__ Cv, int ldc, int K) {
    __shared__ unsigned short As[128][64];
    __shared__ unsigned short Bs[128][64];
    int tid = threadIdx.x;
    int lane = tid & 63, wid = tid >> 6;
    int wr = wid >> 1, wc = wid & 1;

    int bm, bn;
    if ((gridDim.y & 7) == 0) {
        int bid   = blockIdx.y * gridDim.x + blockIdx.x;
        int xcd   = bid & 7;
        int local = bid >> 3;
        int mrows = gridDim.y >> 3;
        bm = (xcd * mrows + (local % mrows)) * 128;
        bn = (local / mrows) * 128;
    } else {
        bm = blockIdx.y * 128;
        bn = blockIdx.x * 128;
    }

    f32x4 acc[4][4];
    #pragma unroll
    for (int i=0;i<4;i++)
        #pragma unroll
        for (int j=0;j<4;j++) acc[i][j] = (f32x4){0.f,0.f,0.f,0.f};

    int srow_off = lane >> 3;
    int sslot    = lane & 7;

    for (int k0 = 0; k0 < K; k0 += 64) {
        #pragma unroll
        for (int q=0;q<4;q++){
            int brow = (wid*4+q)*8;
            int row  = brow + srow_off;
            int sl   = sslot ^ (row & 7);
            gld16(A + (size_t)(bm + row)*lda + k0 + sl*8, &As[brow][0]);
            gld16(B + (size_t)(bn + row)*ldb + k0 + sl*8, &Bs[brow][0]);
        }
        __syncthreads();
        #pragma unroll
        for (int kk=0; kk<64; kk+=32){
            bf16x8 a[4], b[4];
            #pragma unroll
            for (int i=0;i<4;i++){
                int row = wr*64 + i*16 + (lane&15);
                int slot = ((kk>>3) + (lane>>4)) ^ (row & 7);
                a[i] = *(const bf16x8*)&As[row][slot*8];
            }
            #pragma unroll
            for (int j=0;j<4;j++){
                int row = wc*64 + j*16 + (lane&15);
                int slot = ((kk>>3) + (lane>>4)) ^ (row & 7);
                b[j] = *(const bf16x8*)&Bs[row][slot*8];
            }
            #pragma unroll
            for (int i=0;i<4;i++)
                #pragma unroll
                for (int j=0;j<4;j++)
                    acc[i][j] = MFMA16(a[i], b[j], acc[i][j]);
        }
        __syncthreads();
    }
    #pragma unroll
    for (int i=0;i<4;i++){
        int row0 = bm + wr*64 + i*16 + (lane>>4)*4;
        #pragma unroll
        for (int j=0;j<4;j++){
            int col = bn + wc*64 + j*16 + (lane&15);
            #pragma unroll
            for (int r=0;r<4;r++){
                if (BF16OUT)
                    ((unsigned short*)Cv)[(size_t)(row0+r)*ldc + col] = f2bf(acc[i][j][r]);
                else
                    ((float*)Cv)[(size_t)(row0+r)*ldc + col] = acc[i][j][r];
            }
        }
    }
}

// ---------------- fp32→bf16 conversion kernels --------------------------------------
__global__ __launch_bounds__(256) void cvt_bf16(const float* __restrict__ in,
                                                unsigned short* __restrict__ out, size_t n4){
    size_t i4 = (size_t)blockIdx.x*256 + threadIdx.x;
    if (i4 >= n4) return;
    size_t i = i4*4;
    float4 v = *(const float4*)(in+i);
    ushort4 o; o.x=f2bf(v.x); o.y=f2bf(v.y); o.z=f2bf(v.z); o.w=f2bf(v.w);
    *(ushort4*)(out+i) = o;
}
__global__ __launch_bounds__(256) void cvt_w1(const float* __restrict__ in,
                                              unsigned short* __restrict__ out){
    size_t i4 = (size_t)blockIdx.x*256 + threadIdx.x;
    if (i4 >= (size_t)PROJ_PAD*HIDDEN/4) return;
    size_t i = i4*4;
    int row = (int)(i / HIDDEN);
    ushort4 o;
    if (row < PROJ){
        float4 v = *(const float4*)(in+i);
        o.x=f2bf(v.x); o.y=f2bf(v.y); o.z=f2bf(v.z); o.w=f2bf(v.w);
    } else { o.x=o.y=o.z=o.w=0; }
    *(ushort4*)(out+i) = o;
}

// ---------------- split-K fp32 GEMM for the 336 B/C/dt columns ----------------------
#define BM 128
#define BN 128
#define BKK 16
__global__ __launch_bounds__(256) void gemm_bc_splitk(const float* __restrict__ A, int lda,
                                                      const float* __restrict__ B, int ldb,
                                                      float* __restrict__ Cpart) {
    __shared__ float As[BKK][BM];
    __shared__ float Bs[BKK][BN];
    int tid = threadIdx.x;
    int bm = blockIdx.y * BM, bn = blockIdx.x * BN;
    int z  = blockIdx.z;
    int ty = tid >> 4, tx = tid & 15;
    float acc[8][8];
    #pragma unroll
    for (int i=0;i<8;i++)
        #pragma unroll
        for (int j=0;j<8;j++) acc[i][j]=0.f;
    int lr = tid >> 1, lk = (tid & 1) * 8;
    for (int k0 = z*KCH; k0 < (z+1)*KCH; k0 += BKK) {
        #pragma unroll
        for (int u=0;u<8;u++)
            As[lk+u][lr] = A[(size_t)(bm+lr)*lda + k0 + lk + u];
        int ncol = bn + lr;
        if (ncol < NBC) {
            #pragma unroll
            for (int u=0;u<8;u++)
                Bs[lk+u][lr] = B[(size_t)ncol*ldb + k0 + lk + u];
        } else {
            #pragma unroll
            for (int u=0;u<8;u++) Bs[lk+u][lr] = 0.f;
        }
        __syncthreads();
        #pragma unroll
        for (int k=0;k<BKK;k++){
            float a[8], bb[8];
            #pragma unroll
            for (int i=0;i<8;i++) a[i] = As[k][ty*8+i];
            #pragma unroll
            for (int j=0;j<8;j++) bb[j] = Bs[k][tx*8+j];
            #pragma unroll
            for (int i=0;i<8;i++)
                #pragma unroll
                for (int j=0;j<8;j++) acc[i][j] += a[i]*bb[j];
        }
        __syncthreads();
    }
    float* Cz = Cpart + (size_t)z*TOK*NBC;
    #pragma unroll
    for (int i=0;i<8;i++){
        int m = bm + ty*8 + i;
        #pragma unroll
        for (int j=0;j<8;j++){
            int n = bn + tx*8 + j;
            if (n < NBC) Cz[(size_t)m*NBC + n] = acc[i][j];
        }
    }
}

// fixed-order reduce + fused dt softplus
__global__ __launch_bounds__(256) void reduce_bc(const float* __restrict__ part,
                                                 const float* __restrict__ dt_bias,
                                                 float* __restrict__ outBC,
                                                 float* __restrict__ dtbuf) {
    size_t i4 = (size_t)blockIdx.x*256 + threadIdx.x;
    if (i4 >= (size_t)TOK*NBC/4) return;
    size_t i = i4*4;
    float4 s = *(const float4*)(part + i);
    #pragma unroll
    for (int z=1; z<KSPLIT; z++){
        float4 v = *(const float4*)(part + (size_t)z*TOK*NBC + i);
        s.x += v.x; s.y += v.y; s.z += v.z; s.w += v.w;
    }
    int col = (int)(i % NBC);
    int t   = (int)(i / NBC);
    if (col < 256) {
        *(float4*)(outBC + i) = s;
    } else {
        int h = col - 256;
        float e[4] = {s.x, s.y, s.z, s.w};
        #pragma unroll
        for (int u=0;u<4;u++){
            float xv = e[u] + dt_bias[h+u];
            float sp = (xv > 20.f) ? xv : log1pf(expf(xv));
            e[u] = fminf(fmaxf(sp, 0.f), 100.f);
        }
        float4 o; o.x=e[0]; o.y=e[1]; o.z=e[2]; o.w=e[3];
        *(float4*)(dtbuf + (size_t)t*NUM_HEADS + h) = o;
    }
}

// ---------------- conv+SiLU X, transposed output XT[b][d][s] (bf16) -----------------
// block: 64 tokens x 64 dims; coalesced read of proj rows, coalesced write of XT rows.
__global__ __launch_bounds__(256) void conv_xt_kernel(const unsigned short* __restrict__ projb,
                                                      const float* __restrict__ cw,
                                                      const float* __restrict__ cb,
                                                      unsigned short* __restrict__ XT) {
    int t0 = blockIdx.x * 64;
    int d0 = blockIdx.y * 64;
    int b  = t0 / SEQ;
    int s0 = t0 % SEQ;
    __shared__ unsigned short raw[68][66];   // 132B rows: conflict-free column reads
    int tid = threadIdx.x;
    for (int f = tid; f < 67*8; f += 256){
        int r = f >> 3, g = f & 7;
        int sp = s0 - 3 + r;
        uint4 v;
        if (sp >= 0) v = *(const uint4*)(projb + ((size_t)(b*SEQ+sp))*PROJ_PAD + INTER + d0 + g*8);
        else { v.x=0u; v.y=0u; v.z=0u; v.w=0u; }
        unsigned int* dst = (unsigned int*)&raw[r][g*8];
        dst[0]=v.x; dst[1]=v.y; dst[2]=v.z; dst[3]=v.w;
    }
    __syncthreads();
    int t = tid & 63, dg = tid >> 6;
    #pragma unroll
    for (int dd = 0; dd < 16; dd++){
        int d = dg*16 + dd;
        float acc = cb[d0+d];
        #pragma unroll
        for (int j=0;j<CONV_K;j++)
            acc += cw[(d0+d)*CONV_K+j] * bf2f(raw[t+j][d]);
        float val = acc/(1.f+expf(-acc));
        XT[((size_t)(b*INTER + d0 + d))*SEQ + s0 + t] = f2bf(val);
    }
}

// ---------------- conv+SiLU B/C (fp32 out) + bf16 BT[b][n][s] -----------------------
__global__ __launch_bounds__(256) void conv_bc_kernel(const float* __restrict__ projBC,
                                                      const float* __restrict__ cw,
                                                      const float* __restrict__ cb,
                                                      float* __restrict__ xBC_BC,
                                                      unsigned short* __restrict__ BT) {
    int idx = blockIdx.x*256 + threadIdx.x;
    if (idx >= TOK*256) return;
    int d = idx & 255;
    int t = idx >> 8;
    int b = t / SEQ, sl = t % SEQ;
    int dc = INTER + d;
    float acc = cb[dc];
    #pragma unroll
    for (int j=0;j<CONV_K;j++){
        int sp = sl - (CONV_K-1) + j;
        if (sp >= 0)
            acc += cw[dc*CONV_K+j] * projBC[((size_t)(b*SEQ+sp))*NBC + d];
    }
    float val = acc / (1.f + expf(-acc));
    xBC_BC[(size_t)t*256 + d] = val;
    if (d < 128)
        BT[((size_t)(b*128 + d))*SEQ + sl] = f2bf(val);
}

// ---------------- per-chunk inclusive cumsum of dA = A*dt ---------------------------
__global__ __launch_bounds__(256) void cumsum_kernel(const float* __restrict__ dtbuf,
                                                     const float* __restrict__ A_log,
                                                     float* __restrict__ A_cum) {
    int c = blockIdx.x, h = blockIdx.y, b = blockIdx.z;
    int l = threadIdx.x;
    float A = -expf(A_log[h]);
    float v = A * dtbuf[(size_t)(b*SEQ + c*CHUNK + l)*NUM_HEADS + h];
    __shared__ float buf[CHUNK];
    buf[l] = v;
    __syncthreads();
    for (int off=1; off<CHUNK; off<<=1){
        float t = (l>=off) ? buf[l-off] : 0.f;
        __syncthreads();
        buf[l] += t;
        __syncthreads();
    }
    A_cum[((size_t)b*NUM_HEADS + h)*SEQ + c*CHUNK + l] = buf[l];
}

// ---------------- G[l][s] = C[l] . B[s]  (head-shared), bf16, l-major ---------------
__global__ __launch_bounds__(256) void g_kernel(const float* __restrict__ xBC_BC,
                                                unsigned short* __restrict__ G) {
    int p = blockIdx.x, c = blockIdx.y, b = blockIdx.z;
    int lt = 0, a0 = 0;
    while (a0 + lt + 1 <= p) { a0 += lt + 1; lt++; }
    int st = p - a0;
    int l0 = lt*64, s0 = st*64;
    __shared__ float Cs[64][68];
    __shared__ float Bs[64][68];
    int tid = threadIdx.x, ty = tid >> 4, tx = tid & 15;
    float acc[4][4];
    #pragma unroll
    for (int i=0;i<4;i++)
        #pragma unroll
        for (int j=0;j<4;j++) acc[i][j]=0.f;

    size_t rowC = ((size_t)(b*SEQ + c*CHUNK + l0))*256 + 128;
    size_t rowB = ((size_t)(b*SEQ + c*CHUNK + s0))*256;
    for (int kc=0; kc<2; kc++){
        #pragma unroll
        for (int it=0; it<4; it++){
            int f = tid + it*256;
            int r = f >> 4, c4 = f & 15;
            float4 cv = *(const float4*)(xBC_BC + rowC + (size_t)r*256 + kc*64 + c4*4);
            float4 bv = *(const float4*)(xBC_BC + rowB + (size_t)r*256 + kc*64 + c4*4);
            *(float4*)&Cs[r][c4*4] = cv;
            *(float4*)&Bs[r][c4*4] = bv;
        }
        __syncthreads();
        #pragma unroll 8
        for (int k=0;k<64;k++){
            float a[4], bb[4];
            #pragma unroll
            for (int i=0;i<4;i++) a[i] = Cs[ty*4+i][k];
            #pragma unroll
            for (int j=0;j<4;j++) bb[j] = Bs[tx*4+j][k];
            #pragma unroll
            for (int i=0;i<4;i++)
                #pragma unroll
                for (int j=0;j<4;j++) acc[i][j] += a[i]*bb[j];
        }
        __syncthreads();
    }
    size_t Gb = ((size_t)(b*NC + c)) << 16;
    #pragma unroll
    for (int i=0;i<4;i++){
        ushort4 g4;
        g4.x = f2bf(acc[i][0]); g4.y = f2bf(acc[i][1]);
        g4.z = f2bf(acc[i][2]); g4.w = f2bf(acc[i][3]);
        *(ushort4*)(G + Gb + (size_t)(l0 + ty*4 + i)*256 + s0 + tx*4) = g4;
    }
}

// ---------------- statesT[p][n] = sum_l XT[p][l] * (BT[n][l]*w[l])  (MFMA) ----------
__global__ __launch_bounds__(256) void states_mfma(const unsigned short* __restrict__ XT,
                                                   const unsigned short* __restrict__ BT,
                                                   const float* __restrict__ dtbuf,
                                                   const float* __restrict__ A_cum,
                                                   float* __restrict__ statesT) {
    int c = blockIdx.x, h = blockIdx.y, b = blockIdx.z;
    __shared__ unsigned short Asx[64][64];   // XT tile [p][l]  (gld16, swizzled src)
    __shared__ unsigned short Bsw[128][64];  // Bw tile [n][l]  (reg-staged, swizzled)
    __shared__ float wl[CHUNK];
    int tid = threadIdx.x, lane = tid & 63, wid = tid >> 6;
    {
        const float* ac = A_cum + ((size_t)(b*NUM_HEADS+h))*SEQ + c*CHUNK;
        float Alast = ac[CHUNK-1];
        wl[tid] = expf(Alast - ac[tid]) * dtbuf[((size_t)(b*SEQ + c*CHUNK + tid))*NUM_HEADS + h];
    }
    __syncthreads();
    f32x4 acc[4][2];
    #pragma unroll
    for (int i=0;i<4;i++)
        #pragma unroll
        for (int j=0;j<2;j++) acc[i][j] = (f32x4){0.f,0.f,0.f,0.f};

    for (int kc = 0; kc < 4; kc++){
        int lbase = kc*64;
        #pragma unroll
        for (int q=0;q<2;q++){
            int brow = (wid*2+q)*8;
            int row  = brow + (lane>>3);
            int sl   = (lane&7) ^ (row & 7);
            gld16(XT + ((size_t)(b*INTER + h*HEAD_DIM + row))*SEQ + c*CHUNK + lbase + sl*8,
                  &Asx[brow][0]);
        }
        #pragma unroll
        for (int it=0; it<4; it++){
            int f = tid + it*256;
            int r = f >> 3, g = f & 7;
            uint4 v = *(const uint4*)(BT + ((size_t)(b*128 + r))*SEQ + c*CHUNK + lbase + g*8);
            float e[8]; unpack8(v, e);
            unsigned short o[8];
            #pragma unroll
            for (int u=0;u<8;u++) o[u] = f2bf(e[u] * wl[lbase + g*8 + u]);
            int slot = g ^ (r & 7);
            *(ushort4*)&Bsw[r][slot*8]   = *(ushort4*)&o[0];
            *(ushort4*)&Bsw[r][slot*8+4] = *(ushort4*)&o[4];
        }
        __syncthreads();
        #pragma unroll
        for (int kk=0; kk<64; kk+=32){
            bf16x8 a[4], bb[2];
            #pragma unroll
            for (int i=0;i<4;i++){
                int row = i*16 + (lane&15);
                int slot = ((kk>>3)+(lane>>4)) ^ (row&7);
                a[i] = *(const bf16x8*)&Asx[row][slot*8];
            }
            #pragma unroll
            for (int j=0;j<2;j++){
                int row = wid*32 + j*16 + (lane&15);
                int slot = ((kk>>3)+(lane>>4)) ^ (row&7);
                bb[j] = *(const bf16x8*)&Bsw[row][slot*8];
            }
            #pragma unroll
            for (int i=0;i<4;i++)
                #pragma unroll
                for (int j=0;j<2;j++)
                    acc[i][j] = MFMA16(a[i], bb[j], acc[i][j]);
        }
        __syncthreads();
    }
    size_t sb = ((size_t)((b*NC + c)*NUM_HEADS + h))*(HEAD_DIM*STATE);
    #pragma unroll
    for (int i=0;i<4;i++){
        #pragma unroll
        for (int j=0;j<2;j++){
            int n = wid*32 + j*16 + (lane&15);
            int p0 = i*16 + (lane>>4)*4;
            #pragma unroll
            for (int r=0;r<4;r++)
                statesT[sb + (size_t)(p0+r)*128 + n] = acc[i][j][r];
        }
    }
}

// ---------------- inter-chunk recurrence (in place, layout-agnostic) ----------------
__global__ __launch_bounds__(256) void recur_kernel(const float* __restrict__ A_cum,
                                                    float* __restrict__ states) {
    int h = blockIdx.x, b = blockIdx.y;
    int tid = threadIdx.x;
    float Srun[32];
    #pragma unroll
    for (int i=0;i<32;i++) Srun[i]=0.f;
    const float* acum = A_cum + ((size_t)b*NUM_HEADS + h)*SEQ;
    for (int c=0;c<NC;c++){
        float alast = acum[c*CHUNK + CHUNK-1];
        float dec = expf(alast);
        size_t base = ((size_t)((b*NC + c)*NUM_HEADS + h))*(HEAD_DIM*STATE);
        #pragma unroll
        for (int i=0;i<32;i++){
            size_t idx = base + (size_t)tid + (size_t)i*256;
            float raw = states[idx];
            states[idx] = Srun[i];
            Srun[i] = Srun[i]*dec + raw;
        }
    }
}

// ---------------- Y = e_l*(Cs @ St^T) + Gw @ Xs^T + D*X   (MFMA) --------------------
__global__ __launch_bounds__(256) void yscan_mfma(const unsigned short* __restrict__ G,
                                                  const float* __restrict__ xBC_BC,
                                                  const unsigned short* __restrict__ XT,
                                                  const float* __restrict__ dtbuf,
                                                  const float* __restrict__ A_cum,
                                                  const float* __restrict__ statesT,
                                                  const float* __restrict__ Dvec,
                                                  unsigned short* __restrict__ projb) {
    int xb = blockIdx.x;
    int c = xb >> 2, lt = xb & 3;
    int h = blockIdx.y, b = blockIdx.z;
    int l0 = lt*64;
    __shared__ __align__(16) char pool[32768];
    unsigned short (*Cs)[128] = (unsigned short(*)[128])pool;            // [l][n] bf16
    unsigned short (*St)[128] = (unsigned short(*)[128])(pool + 16384);  // [p][n] bf16
    unsigned short (*Gw)[64]  = (unsigned short(*)[64])pool;             // [l][s] bf16
    unsigned short (*Xs)[64]  = (unsigned short(*)[64])(pool + 8192);    // [p][s] bf16
    float (*Ot)[68]           = (float(*)[68])pool;                      // out stage
    __shared__ float ac[CHUNK], dts[CHUNK];
    int tid = threadIdx.x, lane = tid & 63, wid = tid >> 6;
    ac[tid]  = A_cum[((size_t)(b*NUM_HEADS + h))*SEQ + c*CHUNK + tid];
    dts[tid] = dtbuf[((size_t)(b*SEQ + c*CHUNK + tid))*NUM_HEADS + h];
    __syncthreads();

    // ---- phase 1: stage Cs (bf16 from fp32 C cols) and St (bf16 from statesT) ----
    size_t stb = ((size_t)((b*NC + c)*NUM_HEADS + h))*(HEAD_DIM*STATE);
    #pragma unroll
    for (int it=0; it<8; it++){
        int f = tid + it*256;          // 0..2047
        int r = f >> 5, c4 = f & 31;
        float4 v = *(const float4*)(xBC_BC + ((size_t)(b*SEQ + c*CHUNK + l0 + r))*256 + 128 + c4*4);
        unsigned short o[4] = {f2bf(v.x),f2bf(v.y),f2bf(v.z),f2bf(v.w)};
        int col = c4*4;
        int slot = (col>>3) ^ (r&7);
        *(ushort4*)&Cs[r][slot*8 + (col&7)] = *(ushort4*)o;
        float4 w = *(const float4*)(statesT + stb + (size_t)r*128 + c4*4);
        unsigned short o2[4] = {f2bf(w.x),f2bf(w.y),f2bf(w.z),f2bf(w.w)};
        *(ushort4*)&St[r][slot*8 + (col&7)] = *(ushort4*)o2;
    }
    __syncthreads();

    // ---- Y_off MFMAs: wave strip = 16 l-rows; 1 a-frag x 4 b-frags, K=128 ----
    f32x4 acc1[4];
    #pragma unroll
    for (int j=0;j<4;j++) acc1[j] = (f32x4){0.f,0.f,0.f,0.f};
    #pragma unroll
    for (int kk=0; kk<128; kk+=32){
        int arow = wid*16 + (lane&15);
        int aslot = ((kk>>3)+(lane>>4)) ^ (arow&7);
        bf16x8 a = *(const bf16x8*)&Cs[arow][aslot*8];
        #pragma unroll
        for (int j=0;j<4;j++){
            int brow = j*16 + (lane&15);
            int bslot = ((kk>>3)+(lane>>4)) ^ (brow&7);
            bf16x8 bb = *(const bf16x8*)&St[brow][bslot*8];
            acc1[j] = MFMA16(a, bb, acc1[j]);
        }
    }
    float el[4];
    #pragma unroll
    for (int r=0;r<4;r++) el[r] = expf(ac[l0 + wid*16 + (lane>>4)*4 + r]);
    float master[4][4];
    #pragma unroll
    for (int j=0;j<4;j++)
        #pragma unroll
        for (int r=0;r<4;r++) master[j][r] = acc1[j][r]*el[r];
    __syncthreads();   // Cs/St dead; pool reused

    // ---- phase 2: Y_diag over causal s-tiles, accumulate in acc2 ----
    size_t Gb = ((size_t)(b*NC + c)) << 16;
    f32x4 acc2[4];
    #pragma unroll
    for (int j=0;j<4;j++) acc2[j] = (f32x4){0.f,0.f,0.f,0.f};
    for (int st=0; st<=lt; st++){
        int s0 = st*64;
        // Gw = G * w(l,s)  (joint, masked) reg-staged
        #pragma unroll
        for (int it=0; it<2; it++){
            int f = tid + it*256;      // 0..511
            int r = f >> 3, g = f & 7;
            uint4 v = *(const uint4*)(G + Gb + (size_t)(l0 + r)*256 + s0 + g*8);
            float e[8]; unpack8(v, e);
            float acl = ac[l0 + r];
            unsigned short o[8];
            #pragma unroll
            for (int u=0;u<8;u++){
                int s = s0 + g*8 + u;
                float w = (s <= l0 + r) ? expf(acl - ac[s])*dts[s] : 0.f;
                o[u] = f2bf(e[u]*w);
            }
            int slot = g ^ (r&7);
            *(ushort4*)&Gw[r][slot*8]   = *(ushort4*)&o[0];
            *(ushort4*)&Gw[r][slot*8+4] = *(ushort4*)&o[4];
        }
        // Xs: gld16 from XT rows (head window), swizzled source
        #pragma unroll
        for (int q=0;q<2;q++){
            int brow = (wid*2+q)*8;
            int row  = brow + (lane>>3);
            int sl   = (lane&7) ^ (row&7);
            gld16(XT + ((size_t)(b*INTER + h*HEAD_DIM + row))*SEQ + c*CHUNK + s0 + sl*8,
                  &Xs[brow][0]);
        }
        __syncthreads();
        #pragma unroll
        for (int kk=0; kk<64; kk+=32){
            int arow = wid*16 + (lane&15);
            int aslot = ((kk>>3)+(lane>>4)) ^ (arow&7);
            bf16x8 a = *(const bf16x8*)&Gw[arow][aslot*8];
            #pragma unroll
            for (int j=0;j<4;j++){
                int brow = j*16 + (lane&15);
                int bslot = ((kk>>3)+(lane>>4)) ^ (brow&7);
                bf16x8 bb = *(const bf16x8*)&Xs[brow][bslot*8];
                acc2[j] = MFMA16(a, bb, acc2[j]);
            }
        }
        if (st < lt) __syncthreads();   // keep diag Xs resident on last tile
    }

    // ---- combine: + Y_diag + D*X (X[l][p] = Xs[p][l_local] from diag tile) ----
    float Dh = Dvec[h];
    #pragma unroll
    for (int j=0;j<4;j++){
        int p = j*16 + (lane&15);
        #pragma unroll
        for (int r=0;r<4;r++){
            int sl_ = wid*16 + (lane>>4)*4 + r;     // diag s index = local l
            int slot = (sl_>>3) ^ (p&7);
            float xv = bf2f(Xs[p][slot*8 + (sl_&7)]);
            master[j][r] += acc2[j][r] + Dh*xv;
        }
    }
    __syncthreads();   // Xs dead; pool reused for Ot

    #pragma unroll
    for (int j=0;j<4;j++){
        int p = j*16 + (lane&15);
        #pragma unroll
        for (int r=0;r<4;r++)
            Ot[wid*16 + (lane>>4)*4 + r][p] = master[j][r];
    }
    __syncthreads();
    #pragma unroll
    for (int it=0; it<4; it++){
        int f = tid + it*256;
        int r = f >> 4, c4 = f & 15;
        ushort4 o;
        o.x = f2bf(Ot[r][c4*4+0]); o.y = f2bf(Ot[r][c4*4+1]);
        o.z = f2bf(Ot[r][c4*4+2]); o.w = f2bf(Ot[r][c4*4+3]);
        *(ushort4*)(projb + ((size_t)(b*SEQ + c*CHUNK + l0 + r))*PROJ_PAD + INTER + h*HEAD_DIM + c4*4) = o;
    }
}

// ---------------- gate * silu + RMSNorm -> packed bf16 y ----------------------------
__global__ __launch_bounds__(256) void gate_norm_kernel(const unsigned short* __restrict__ projb,
                                                        const float* __restrict__ normw,
                                                        unsigned short* __restrict__ yb) {
    int t = blockIdx.x;
    int tid = threadIdx.x;
    const unsigned short* row = projb + (size_t)t*PROJ_PAD;
    __shared__ float red[4];
    float vals[20];
    float ss = 0.f;
    #pragma unroll
    for (int i=0;i<5;i++){
        int j = (tid + i*256)*4;
        ushort4 g4 = *(const ushort4*)(row + j);
        ushort4 y4 = *(const ushort4*)(row + INTER + j);
        #pragma unroll
        for (int u=0;u<4;u++){
            float g = bf2f(((const unsigned short*)&g4)[u]);
            float y = bf2f(((const unsigned short*)&y4)[u]);
            float gv = g / (1.f + expf(-g));
            float v = y * gv;
            vals[i*4+u] = v;
            ss += v*v;
        }
    }
    #pragma unroll
    for (int off=32; off; off>>=1) ss += __shfl_xor(ss, off);
    if ((tid&63)==0) red[tid>>6] = ss;
    __syncthreads();
    float tot = red[0]+red[1]+red[2]+red[3];
    float inv = rsqrtf(tot/(float)INTER + EPS);
    #pragma unroll
    for (int i=0;i<5;i++){
        int j = (tid + i*256)*4;
        ushort4 o;
        o.x = f2bf(vals[i*4+0] * inv * normw[j+0]);
        o.y = f2bf(vals[i*4+1] * inv * normw[j+1]);
        o.z = f2bf(vals[i*4+2] * inv * normw[j+2]);
        o.w = f2bf(vals[i*4+3] * inv * normw[j+3]);
        *(ushort4*)(yb + (size_t)t*INTER + j) = o;
    }
}

// ------------------------------------------------------------------------------------
extern "C" void kernel_launch(void* const* d_in, const int* in_sizes, int n_in,
                              void* d_out, int out_size, void* d_ws, size_t ws_size,
                              hipStream_t stream) {
    const float* x        = (const float*)d_in[0];
    const float* in_w     = (const float*)d_in[1];
    const float* conv_w   = (const float*)d_in[2];
    const float* conv_b   = (const float*)d_in[3];
    const float* A_log    = (const float*)d_in[4];
    const float* Dvec     = (const float*)d_in[5];
    const float* dt_bias  = (const float*)d_in[6];
    const float* norm_w   = (const float*)d_in[7];
    const float* out_w    = (const float*)d_in[8];
    float* out = (float*)d_out;
    (void)ws_size; (void)n_in; (void)in_sizes; (void)out_size;

    // ---- workspace layout (bytes), total ~276 MB ----
    const size_t PROJB   = (size_t)TOK*PROJ_PAD*2;          // 87.0 MB
    const size_t PROJBCB = (size_t)TOK*NBC*4;               //  5.5 MB
    const size_t XTB     = (size_t)TOK*INTER*2;             // 41.9 MB (transposed X)
    const size_t XBCBCB  = (size_t)TOK*256*4;               //  4.2 MB
    const size_t BTB     = (size_t)BATCH*128*SEQ*2;         //  1.0 MB
    const size_t GBYTES  = (size_t)BATCH*NC*CHUNK*CHUNK*2;  //  2.1 MB
    const size_t DTB     = (size_t)TOK*NUM_HEADS*4;         //  1.3 MB
    const size_t ACUMB   = DTB;
    const size_t STB     = (size_t)BATCH*NC*NUM_HEADS*HEAD_DIM*STATE*4; // 41.9 MB
    const size_t XB      = (size_t)TOK*HIDDEN*2;
    const size_t YB      = (size_t)TOK*INTER*2;

    char* base = (char*)d_ws;
    size_t off = 0;
    unsigned short* projb  = (unsigned short*)(base + off); off += PROJB;
    float* projBC          = (float*)(base + off);          off += PROJBCB;
    unsigned short* XTp    = (unsigned short*)(base + off); off += XTB;
    float* xBC_BC          = (float*)(base + off);          off += XBCBCB;
    unsigned short* BTp    = (unsigned short*)(base + off); off += BTB;
    unsigned short* Gp     = (unsigned short*)(base + off); off += GBYTES;
    float* dtbuf           = (float*)(base + off);          off += DTB;
    float* A_cum           = (float*)(base + off);          off += ACUMB;
    float* statesT         = (float*)(base + off);          off += STB;
    char*  T               = base + off;
    unsigned short* xb  = (unsigned short*)T;
    unsigned short* w1b = (unsigned short*)(T + XB);
    float* bcpart       = (float*)T;                   // split-K partials (88 MB)
    unsigned short* yb  = (unsigned short*)T;
    unsigned short* w2b = (unsigned short*)(T + YB);

    const size_t XB_E = (size_t)TOK*HIDDEN;
    const size_t W1_E = (size_t)PROJ_PAD*HIDDEN;
    const size_t W2_E = (size_t)HIDDEN*INTER;

    // 0. conversions for GEMM1
    cvt_bf16<<<(unsigned)((XB_E/4+255)/256), 256, 0, stream>>>(x, xb, XB_E/4);
    cvt_w1<<<(unsigned)((W1_E/4+255)/256), 256, 0, stream>>>(in_w, w1b);

    // 1. proj = x @ in_w^T  (bf16 MFMA, bf16 out, XCD swizzle)
    gemm_bf16<true><<<dim3(PROJ_PAD/128, TOK/128), 256, 0, stream>>>(xb, HIDDEN, w1b, HIDDEN,
                                                                     projb, PROJ_PAD, HIDDEN);
    // 1b. B/C/dt columns in fp32 via split-K
    gemm_bc_splitk<<<dim3((NBC+BN-1)/BN, TOK/BM, KSPLIT), 256, 0, stream>>>(
        x, HIDDEN, in_w + (size_t)(INTER+INTER)*HIDDEN, HIDDEN, bcpart);
    reduce_bc<<<(unsigned)(((size_t)TOK*NBC/4+255)/256), 256, 0, stream>>>(bcpart, dt_bias, projBC, dtbuf);

    // 2. conv + silu
    conv_xt_kernel<<<dim3(TOK/64, INTER/64), 256, 0, stream>>>(projb, conv_w, conv_b, XTp);
    conv_bc_kernel<<<(TOK*256+255)/256, 256, 0, stream>>>(projBC, conv_w, conv_b, xBC_BC, BTp);
    // 2b. w2 conversion (after reduce consumed partials)
    cvt_bf16<<<(unsigned)((W2_E/4+255)/256), 256, 0, stream>>>(out_w, w2b, W2_E/4);
    // 3. cumsum
    cumsum_kernel<<<dim3(NC, NUM_HEADS, BATCH), 256, 0, stream>>>(dtbuf, A_log, A_cum);
    // 4. G = C.B^T (head-shared), [l][s] layout
    g_kernel<<<dim3(10, NC, BATCH), 256, 0, stream>>>(xBC_BC, Gp);
    // 5. per-chunk states (MFMA) -> statesT[p][n]
    states_mfma<<<dim3(NC, NUM_HEADS, BATCH), 256, 0, stream>>>(XTp, BTp, dtbuf, A_cum, statesT);
    // 6. inter-chunk recurrence
    recur_kernel<<<dim3(NUM_HEADS, BATCH), 256, 0, stream>>>(A_cum, statesT);
    // 7. Y (MFMA) -> bf16 into projb
    yscan_mfma<<<dim3(NC*4, NUM_HEADS, BATCH), 256, 0, stream>>>(Gp, xBC_BC, XTp, dtbuf, A_cum,
                                                                 statesT, Dvec, projb);
    // 8. gate + RMSNorm -> bf16 y
    gate_norm_kernel<<<TOK, 256, 0, stream>>>(projb, norm_w, yb);
    // 9. out = y @ out_w^T  (bf16 MFMA, fp32 out, XCD swizzle)
    gemm_bf16<false><<<dim3(HIDDEN/128, TOK/128), 256, 0, stream>>>(yb, INTER, w2b, INTER,
                                                                    out, HIDDEN, INTER);
}